// Round 7
// baseline (332.055 us; speedup 1.0000x reference)
//
#include <hip/hip_runtime.h>
#include <cmath>

#define B_   128
#define L_   256
#define HID_ 768
#define HID2_ 1536
#define CDIM_ 192
#define SDIM_ 128
#define NPROJ_ 128
#define FDIM_ 321

typedef __attribute__((ext_vector_type(8))) short bf16x8;
typedef __attribute__((ext_vector_type(4))) float f32x4;

__device__ inline unsigned short bf_hi_trunc(float x) {
    return (unsigned short)(__float_as_uint(x) >> 16);
}
__device__ inline float bf2f(unsigned short s) {
    return __uint_as_float(((unsigned int)s) << 16);
}
__device__ inline unsigned short f2bf_rne(float x) {
    unsigned int u = __float_as_uint(x);
    unsigned int r = (u + 0x7fff + ((u >> 16) & 1)) >> 16;
    return (unsigned short)r;
}

// ---------------------------------------------------------------------------
// Kernel P: fused pre-pass. Blocks [0,128): proj_dirs fp32 -> bf16 hi/lo.
// Blocks [128,1152): stats partial masked sums (b = (bid-128)>>3, 32 l-rows).
// 192 threads both.
// ---------------------------------------------------------------------------
__global__ __launch_bounds__(192) void pre_kernel(
    const float* __restrict__ Pd, unsigned short* __restrict__ Pjh,
    unsigned short* __restrict__ Pjl,
    const float* __restrict__ H, const int* __restrict__ tt,
    const int* __restrict__ mm, float* __restrict__ part)
{
    int tid = threadIdx.x;
    if (blockIdx.x < 128) {
        int i = blockIdx.x * 192 + tid;       // float4 index, total 24576
        float4 v = ((const float4*)Pd)[i];
        ushort4 h, l;
        h.x = bf_hi_trunc(v.x); l.x = f2bf_rne(v.x - bf2f(h.x));
        h.y = bf_hi_trunc(v.y); l.y = f2bf_rne(v.y - bf2f(h.y));
        h.z = bf_hi_trunc(v.z); l.z = f2bf_rne(v.z - bf2f(h.z));
        h.w = bf_hi_trunc(v.w); l.w = f2bf_rne(v.w - bf2f(h.w));
        ((ushort4*)Pjh)[i] = h;
        ((ushort4*)Pjl)[i] = l;
        return;
    }
    int bid = blockIdx.x - 128;
    int b  = bid >> 3;
    int pr = bid & 7;

    __shared__ float sf0[32], sf1[32];
    if (tid < 32) {
        int l = pr * 32 + tid;
        int t = tt[b * L_ + l];
        int mv = mm[b * L_ + l];
        sf0[tid] = (t == 0 && mv == 1) ? 1.f : 0.f;
        sf1[tid] = (t == 1 && mv == 1) ? 1.f : 0.f;
    }
    __syncthreads();

    const float* Hb = H + ((size_t)(b * L_ + pr * 32)) * HID_;
    float4 a0 = make_float4(0.f, 0.f, 0.f, 0.f);
    float4 a1 = make_float4(0.f, 0.f, 0.f, 0.f);
    for (int l = 0; l < 32; ++l) {
        float4 x = *(const float4*)(Hb + (size_t)l * HID_ + tid * 4);
        float f0 = sf0[l], f1 = sf1[l];
        a0.x += x.x * f0; a0.y += x.y * f0; a0.z += x.z * f0; a0.w += x.w * f0;
        a1.x += x.x * f1; a1.y += x.y * f1; a1.z += x.z * f1; a1.w += x.w * f1;
    }
    float* dst = part + ((size_t)(b * 8 + pr)) * HID2_;
    *(float4*)(dst + tid * 4) = a0;
    *(float4*)(dst + HID_ + tid * 4) = a1;
}

// ---------------------------------------------------------------------------
// Kernel C: split-bf16 MFMA GEMM v3 (unchanged from R6).
// Runs right after pre_kernel -> H is L3-hot from the stats read.
// ---------------------------------------------------------------------------
#define LDSROW 72   // bf16 per H row: [0:32) hi | [32:64) lo | pad
__global__ __launch_bounds__(256, 2) void gemm_mfma(
    const float* __restrict__ H, const unsigned short* __restrict__ Pjh,
    const unsigned short* __restrict__ Pjl, float* __restrict__ Pt)
{
    __shared__ unsigned short Hs[2][64 * LDSROW];

    int tid = threadIdx.x;
    int w = tid >> 6;
    int lane = tid & 63;
    int c = lane & 15;
    int q = lane >> 4;

    int b = blockIdx.x >> 2;
    int lbase = (blockIdx.x & 3) * 64;

    const float* Hbase = H + ((size_t)(b * L_ + lbase)) * HID_;

    int hrow0 = tid >> 3;          // 0..31
    int hc4   = tid & 7;           // float4 within 32-k row

    const unsigned short* pjh0 = Pjh + (size_t)(w * 32 + c) * HID_ + q * 8;
    const unsigned short* pjh1 = Pjh + (size_t)(w * 32 + 16 + c) * HID_ + q * 8;
    const unsigned short* pjl0 = Pjl + (size_t)(w * 32 + c) * HID_ + q * 8;
    const unsigned short* pjl1 = Pjl + (size_t)(w * 32 + 16 + c) * HID_ + q * 8;

    f32x4 acc[2][4] = {};

    float4 hreg[2];
    uint4 cah[2], cal[2];
    uint4 nah[2], nal[2];

    hreg[0] = *(const float4*)(Hbase + (size_t)hrow0 * HID_ + hc4 * 4);
    hreg[1] = *(const float4*)(Hbase + (size_t)(hrow0 + 32) * HID_ + hc4 * 4);
    cah[0] = *(const uint4*)(pjh0);
    cah[1] = *(const uint4*)(pjh1);
    cal[0] = *(const uint4*)(pjl0);
    cal[1] = *(const uint4*)(pjl1);
#pragma unroll
    for (int u = 0; u < 2; ++u) {
        int row = hrow0 + u * 32;
        float4 v = hreg[u];
        ushort4 h, l;
        h.x = bf_hi_trunc(v.x); l.x = f2bf_rne(v.x - bf2f(h.x));
        h.y = bf_hi_trunc(v.y); l.y = f2bf_rne(v.y - bf2f(h.y));
        h.z = bf_hi_trunc(v.z); l.z = f2bf_rne(v.z - bf2f(h.z));
        h.w = bf_hi_trunc(v.w); l.w = f2bf_rne(v.w - bf2f(h.w));
        *(ushort4*)&Hs[0][row * LDSROW + hc4 * 4]      = h;
        *(ushort4*)&Hs[0][row * LDSROW + 32 + hc4 * 4] = l;
    }
    __syncthreads();

    for (int it = 0; it < 24; ++it) {
        int cur = it & 1;
        int nxt = cur ^ 1;

        if (it + 1 < 24) {
            int k0 = (it + 1) * 32;
            hreg[0] = *(const float4*)(Hbase + (size_t)hrow0 * HID_ + k0 + hc4 * 4);
            hreg[1] = *(const float4*)(Hbase + (size_t)(hrow0 + 32) * HID_ + k0 + hc4 * 4);
            nah[0] = *(const uint4*)(pjh0 + k0);
            nah[1] = *(const uint4*)(pjh1 + k0);
            nal[0] = *(const uint4*)(pjl0 + k0);
            nal[1] = *(const uint4*)(pjl1 + k0);
        }

        bf16x8 bh[4], bl[4];
#pragma unroll
        for (int lt = 0; lt < 4; ++lt) {
            int l = lt * 16 + c;
            bh[lt] = *(const bf16x8*)&Hs[cur][l * LDSROW + q * 8];
            bl[lt] = *(const bf16x8*)&Hs[cur][l * LDSROW + 32 + q * 8];
        }
        bf16x8 ah[2], al[2];
        ah[0] = *(bf16x8*)&cah[0]; ah[1] = *(bf16x8*)&cah[1];
        al[0] = *(bf16x8*)&cal[0]; al[1] = *(bf16x8*)&cal[1];

#pragma unroll
        for (int pt = 0; pt < 2; ++pt)
#pragma unroll
        for (int lt = 0; lt < 4; ++lt) {
            acc[pt][lt] = __builtin_amdgcn_mfma_f32_16x16x32_bf16(ah[pt], bh[lt], acc[pt][lt], 0, 0, 0);
            acc[pt][lt] = __builtin_amdgcn_mfma_f32_16x16x32_bf16(ah[pt], bl[lt], acc[pt][lt], 0, 0, 0);
            acc[pt][lt] = __builtin_amdgcn_mfma_f32_16x16x32_bf16(al[pt], bh[lt], acc[pt][lt], 0, 0, 0);
        }

        if (it + 1 < 24) {
#pragma unroll
            for (int u = 0; u < 2; ++u) {
                int row = hrow0 + u * 32;
                float4 v = hreg[u];
                ushort4 h, l;
                h.x = bf_hi_trunc(v.x); l.x = f2bf_rne(v.x - bf2f(h.x));
                h.y = bf_hi_trunc(v.y); l.y = f2bf_rne(v.y - bf2f(h.y));
                h.z = bf_hi_trunc(v.z); l.z = f2bf_rne(v.z - bf2f(h.z));
                h.w = bf_hi_trunc(v.w); l.w = f2bf_rne(v.w - bf2f(h.w));
                *(ushort4*)&Hs[nxt][row * LDSROW + hc4 * 4]      = h;
                *(ushort4*)&Hs[nxt][row * LDSROW + 32 + hc4 * 4] = l;
            }
            cah[0] = nah[0]; cah[1] = nah[1];
            cal[0] = nal[0]; cal[1] = nal[1];
        }
        __syncthreads();
    }

#pragma unroll
    for (int pt = 0; pt < 2; ++pt)
#pragma unroll
    for (int lt = 0; lt < 4; ++lt)
#pragma unroll
    for (int r = 0; r < 4; ++r) {
        int p = w * 32 + pt * 16 + q * 4 + r;
        int l = lbase + lt * 16 + c;
        Pt[((size_t)(b * NPROJ_ + p)) * L_ + l] = acc[pt][lt][r];
    }
}

// ---------------------------------------------------------------------------
// Kernel FH: fused stats-finalize + head. One block per b, 256 threads.
// Phase 1: rep (cls | mean0-mean1) built in LDS only (never hits global).
// Phase 2: 4 waves x 80 rounds of 1536-dot against Wc/Ws.
// ---------------------------------------------------------------------------
__global__ __launch_bounds__(256) void finhead_kernel(
    const float* __restrict__ H, const int* __restrict__ tt,
    const int* __restrict__ mm, const float* __restrict__ part,
    const float* __restrict__ Wc, const float* __restrict__ bc,
    const float* __restrict__ Ws, const float* __restrict__ bs,
    const float* __restrict__ gate, float* __restrict__ fused)
{
    __shared__ float srep[HID2_];

    int b = blockIdx.x;
    int tid = threadIdx.x;
    int t = tt[b * L_ + tid];
    int mv = mm[b * L_ + tid];
    int n0 = __syncthreads_count(t == 0 && mv == 1);
    int n1 = __syncthreads_count(t == 1 && mv == 1);
    float r0 = 1.f / fmaxf((float)n0, 1.f);
    float r1 = 1.f / fmaxf((float)n1, 1.f);

    const float* pp = part + (size_t)b * 8 * HID2_;
    for (int h = tid; h < HID_; h += 256) {
        float a0 = 0.f, a1 = 0.f;
#pragma unroll
        for (int q = 0; q < 8; ++q) {
            a0 += pp[(size_t)q * HID2_ + h];
            a1 += pp[(size_t)q * HID2_ + HID_ + h];
        }
        srep[h] = H[(size_t)b * L_ * HID_ + h];   // cls
        srep[HID_ + h] = a0 * r0 - a1 * r1;
    }
    __syncthreads();

    int w = tid >> 6;
    int lane = tid & 63;
    float g = 1.0f / (1.0f + expf(-gate[0]));

    for (int i = 0; i < 80; ++i) {
        int o = i * 4 + w;
        bool isC = (o < CDIM_);
        const float4* wr = (const float4*)(isC ? (Wc + (size_t)o * HID2_)
                                               : (Ws + (size_t)(o - CDIM_) * HID2_));
        float acc = 0.f;
#pragma unroll
        for (int u = 0; u < 6; ++u) {
            int k4 = lane + u * 64;
            float4 a = *(const float4*)&srep[k4 * 4];
            float4 ww = wr[k4];
            acc += a.x * ww.x + a.y * ww.y + a.z * ww.z + a.w * ww.w;
        }
        for (int off = 32; off; off >>= 1) acc += __shfl_xor(acc, off, 64);
        if (lane == 0) {
            float bias = isC ? bc[o] : bs[o - CDIM_];
            float scale = isC ? (1.0f - g) : g;
            fused[(size_t)b * (CDIM_ + SDIM_) + o] = (acc + bias) * scale;
        }
    }
}

// ---------------------------------------------------------------------------
// Kernel D: merged-sort W1 distance, contiguous-element bitonic (unchanged)
// ---------------------------------------------------------------------------
__global__ __launch_bounds__(256) void ot_kernel(
    const float* __restrict__ Pt, const int* __restrict__ tt,
    const int* __restrict__ mm, float* __restrict__ dist)
{
    int w = blockIdx.x * 4 + (threadIdx.x >> 6);
    int lane = threadIdx.x & 63;
    int b = w >> 7;
    int p = w & (NPROJ_ - 1);

    float4 pv = *(const float4*)(Pt + ((size_t)(b * NPROJ_ + p)) * L_ + lane * 4);
    int4 t4 = *(const int4*)(tt + (size_t)b * L_ + lane * 4);
    int4 m4 = *(const int4*)(mm + (size_t)b * L_ + lane * 4);

    float pvals[4] = {pv.x, pv.y, pv.z, pv.w};
    int tv[4] = {t4.x, t4.y, t4.z, t4.w};
    int mv[4] = {m4.x, m4.y, m4.z, m4.w};

    unsigned key[4];
#pragma unroll
    for (int r = 0; r < 4; ++r) {
        unsigned u = __float_as_uint(pvals[r]);
        unsigned s = (u & 0x80000000u) ? ~u : (u | 0x80000000u);
        unsigned label = (mv[r] == 1) ? (unsigned)tv[r] : 2u;
        key[r] = (s & ~3u) | label;
    }

    {   // k=2, j=1
        unsigned mn0 = min(key[0], key[1]), mx0 = max(key[0], key[1]);
        key[0] = mn0; key[1] = mx0;
        unsigned mn1 = min(key[2], key[3]), mx1 = max(key[2], key[3]);
        key[2] = mx1; key[3] = mn1;
    }
#pragma unroll
    for (int k = 4; k <= 256; k <<= 1) {
        bool up = (lane & (k >> 2)) == 0;
#pragma unroll
        for (int j = k >> 1; j >= 4; j >>= 1) {
            int lj = j >> 2;
#pragma unroll
            for (int r = 0; r < 4; ++r) {
                unsigned o = (unsigned)__shfl_xor((int)key[r], lj, 64);
                bool lower = (lane & lj) == 0;
                unsigned mn = min(key[r], o), mx = max(key[r], o);
                key[r] = (lower == up) ? mn : mx;
            }
        }
        {   // j=2
            unsigned mn0 = min(key[0], key[2]), mx0 = max(key[0], key[2]);
            key[0] = up ? mn0 : mx0; key[2] = up ? mx0 : mn0;
            unsigned mn1 = min(key[1], key[3]), mx1 = max(key[1], key[3]);
            key[1] = up ? mn1 : mx1; key[3] = up ? mx1 : mn1;
        }
        {   // j=1
            unsigned mn0 = min(key[0], key[1]), mx0 = max(key[0], key[1]);
            key[0] = up ? mn0 : mx0; key[1] = up ? mx0 : mn0;
            unsigned mn1 = min(key[2], key[3]), mx1 = max(key[2], key[3]);
            key[2] = up ? mn1 : mx1; key[3] = up ? mx1 : mn1;
        }
    }

    int lab[4];
    float tval[4];
    unsigned sincl[4];
    unsigned run = 0;
#pragma unroll
    for (int r = 0; r < 4; ++r) {
        lab[r] = (int)(key[r] & 3u);
        unsigned s = key[r] & ~3u;
        unsigned u = (s & 0x80000000u) ? (s ^ 0x80000000u) : ~s;
        tval[r] = __uint_as_float(u);
        unsigned unit = ((lab[r] == 0) ? 0x10000u : 0u) | ((lab[r] == 1) ? 1u : 0u);
        run += unit;
        sincl[r] = run;
    }
    unsigned inc = run;
#pragma unroll
    for (int d = 1; d < 64; d <<= 1) {
        unsigned t = (unsigned)__shfl_up((int)inc, d, 64);
        if (lane >= d) inc += t;
    }
    unsigned ex = inc - run;
    unsigned total = (unsigned)__shfl((int)inc, 63, 64);
    int n0 = (int)(total >> 16), n1 = (int)(total & 0xffffu);
    int m = (n0 < n1) ? n0 : n1;

    float ssum = 0.f;
#pragma unroll
    for (int r = 0; r < 4; ++r) {
        unsigned C = ex + sincl[r];
        int c0 = (int)(C >> 16), c1 = (int)(C & 0xffffu);
        int s0 = (lab[r] == 0), s1 = (lab[r] == 1);
        int wi = abs(min(c0, m) - min(c1, m));
        int wp = abs(min(c0 - s0, m) - min(c1 - s1, m));
        ssum += tval[r] * (float)(wp - wi);
    }
    for (int off = 32; off; off >>= 1) ssum += __shfl_xor(ssum, off, 64);
    if (lane == 0) dist[b * NPROJ_ + p] = ssum / (float)((m > 1) ? m : 1);
}

// ---------------------------------------------------------------------------
// Kernel E: max over p, layernorm, classifier (unchanged)
// ---------------------------------------------------------------------------
__global__ __launch_bounds__(64) void final_kernel(
    const float* __restrict__ fused, const float* __restrict__ dist,
    const float* __restrict__ ln_g, const float* __restrict__ ln_b,
    const float* __restrict__ Wcls, const float* __restrict__ bcls,
    float* __restrict__ out)
{
    int b = blockIdx.x;
    int lane = threadIdx.x;

    float mx = fmaxf(dist[b * NPROJ_ + lane], dist[b * NPROJ_ + 64 + lane]);
    for (int off = 32; off; off >>= 1) mx = fmaxf(mx, __shfl_xor(mx, off, 64));

    float fv[6];
    float sum = 0.f, sq = 0.f;
#pragma unroll
    for (int u = 0; u < 6; ++u) {
        int j = lane + u * 64;
        float x = 0.f;
        if (j < CDIM_ + SDIM_) x = fused[(size_t)b * (CDIM_ + SDIM_) + j];
        else if (j == CDIM_ + SDIM_) x = mx;
        fv[u] = x;
        if (j < FDIM_) { sum += x; sq += x * x; }
    }
    for (int off = 32; off; off >>= 1) {
        sum += __shfl_xor(sum, off, 64);
        sq  += __shfl_xor(sq,  off, 64);
    }
    float mu = sum / (float)FDIM_;
    float var = sq / (float)FDIM_ - mu * mu;
    float inv = rsqrtf(var + 1e-5f);

    float d0 = 0.f, d1 = 0.f;
#pragma unroll
    for (int u = 0; u < 6; ++u) {
        int j = lane + u * 64;
        if (j < FDIM_) {
            float nx = (fv[u] - mu) * inv * ln_g[j] + ln_b[j];
            d0 += nx * Wcls[j];
            d1 += nx * Wcls[FDIM_ + j];
        }
    }
    for (int off = 32; off; off >>= 1) {
        d0 += __shfl_xor(d0, off, 64);
        d1 += __shfl_xor(d1, off, 64);
    }
    if (lane == 0) {
        out[b * 2 + 0] = d0 + bcls[0];
        out[b * 2 + 1] = d1 + bcls[1];
    }
}

// ---------------------------------------------------------------------------
extern "C" void kernel_launch(void* const* d_in, const int* in_sizes, int n_in,
                              void* d_out, int out_size, void* d_ws, size_t ws_size,
                              hipStream_t stream)
{
    const float* H    = (const float*)d_in[0];
    const int*   tt   = (const int*)d_in[1];
    const int*   mm   = (const int*)d_in[2];
    const float* Wc   = (const float*)d_in[3];
    const float* bc   = (const float*)d_in[4];
    const float* Ws   = (const float*)d_in[5];
    const float* bs   = (const float*)d_in[6];
    const float* gate = (const float*)d_in[7];
    const float* ln_g = (const float*)d_in[8];
    const float* ln_b = (const float*)d_in[9];
    const float* Wcls = (const float*)d_in[10];
    const float* bcls = (const float*)d_in[11];
    const float* Pd   = (const float*)d_in[12];
    float* out = (float*)d_out;

    float* ws = (float*)d_ws;
    float* Pt    = ws;                                       // 4194304 fl
    float* part  = Pt + (size_t)B_ * NPROJ_ * L_;            // 128*8*1536 fl (no alias now)
    float* fused = part + (size_t)B_ * 8 * HID2_;            // 128*320 fl
    float* dist  = fused + (size_t)B_ * (CDIM_ + SDIM_);     // 128*128 fl
    unsigned short* Pjh = (unsigned short*)(dist + (size_t)B_ * NPROJ_);
    unsigned short* Pjl = Pjh + (size_t)NPROJ_ * HID_;

    // pre: conv (128 blocks) + stats partials (1024 blocks)
    pre_kernel<<<128 + B_ * 8, 192, 0, stream>>>(Pd, Pjh, Pjl, H, tt, mm, part);
    // gemm immediately after: H is L3-hot from the stats read
    gemm_mfma<<<B_ * 4, 256, 0, stream>>>(H, Pjh, Pjl, Pt);
    finhead_kernel<<<B_, 256, 0, stream>>>(H, tt, mm, part, Wc, bc, Ws, bs, gate, fused);
    ot_kernel<<<B_ * NPROJ_ / 4, 256, 0, stream>>>(Pt, tt, mm, dist);
    final_kernel<<<B_, 64, 0, stream>>>(fused, dist, ln_g, ln_b, Wcls, bcls, out);
}

// Round 8
// 249.758 us; speedup vs baseline: 1.3295x; 1.3295x over previous
//
#include <hip/hip_runtime.h>
#include <cmath>

#define B_   128
#define L_   256
#define HID_ 768
#define HID2_ 1536
#define CDIM_ 192
#define SDIM_ 128
#define NPROJ_ 128
#define FDIM_ 321

typedef __attribute__((ext_vector_type(8))) short bf16x8;
typedef __attribute__((ext_vector_type(4))) float f32x4;

__device__ inline unsigned short bf_hi_trunc(float x) {
    return (unsigned short)(__float_as_uint(x) >> 16);
}
__device__ inline float bf2f(unsigned short s) {
    return __uint_as_float(((unsigned int)s) << 16);
}
__device__ inline unsigned short f2bf_rne(float x) {
    unsigned int u = __float_as_uint(x);
    unsigned int r = (u + 0x7fff + ((u >> 16) & 1)) >> 16;
    return (unsigned short)r;
}

// ---------------------------------------------------------------------------
// Kernel P: fused pre-pass. Blocks [0,128): proj_dirs fp32 -> bf16 hi/lo.
// Blocks [128,1152): stats partial masked sums (32 l-rows each).
// ---------------------------------------------------------------------------
__global__ __launch_bounds__(192) void pre_kernel(
    const float* __restrict__ Pd, unsigned short* __restrict__ Pjh,
    unsigned short* __restrict__ Pjl,
    const float* __restrict__ H, const int* __restrict__ tt,
    const int* __restrict__ mm, float* __restrict__ part)
{
    int tid = threadIdx.x;
    if (blockIdx.x < 128) {
        int i = blockIdx.x * 192 + tid;       // float4 index, total 24576
        float4 v = ((const float4*)Pd)[i];
        ushort4 h, l;
        h.x = bf_hi_trunc(v.x); l.x = f2bf_rne(v.x - bf2f(h.x));
        h.y = bf_hi_trunc(v.y); l.y = f2bf_rne(v.y - bf2f(h.y));
        h.z = bf_hi_trunc(v.z); l.z = f2bf_rne(v.z - bf2f(h.z));
        h.w = bf_hi_trunc(v.w); l.w = f2bf_rne(v.w - bf2f(h.w));
        ((ushort4*)Pjh)[i] = h;
        ((ushort4*)Pjl)[i] = l;
        return;
    }
    int bid = blockIdx.x - 128;
    int b  = bid >> 3;
    int pr = bid & 7;

    __shared__ float sf0[32], sf1[32];
    if (tid < 32) {
        int l = pr * 32 + tid;
        int t = tt[b * L_ + l];
        int mv = mm[b * L_ + l];
        sf0[tid] = (t == 0 && mv == 1) ? 1.f : 0.f;
        sf1[tid] = (t == 1 && mv == 1) ? 1.f : 0.f;
    }
    __syncthreads();

    const float* Hb = H + ((size_t)(b * L_ + pr * 32)) * HID_;
    float4 a0 = make_float4(0.f, 0.f, 0.f, 0.f);
    float4 a1 = make_float4(0.f, 0.f, 0.f, 0.f);
    for (int l = 0; l < 32; ++l) {
        float4 x = *(const float4*)(Hb + (size_t)l * HID_ + tid * 4);
        float f0 = sf0[l], f1 = sf1[l];
        a0.x += x.x * f0; a0.y += x.y * f0; a0.z += x.z * f0; a0.w += x.w * f0;
        a1.x += x.x * f1; a1.y += x.y * f1; a1.z += x.z * f1; a1.w += x.w * f1;
    }
    float* dst = part + ((size_t)(b * 8 + pr)) * HID2_;
    *(float4*)(dst + tid * 4) = a0;
    *(float4*)(dst + HID_ + tid * 4) = a1;
}

// ---------------------------------------------------------------------------
// Kernel C: split-bf16 MFMA GEMM v3 (unchanged from R6).
// ---------------------------------------------------------------------------
#define LDSROW 72   // bf16 per H row: [0:32) hi | [32:64) lo | pad
__global__ __launch_bounds__(256, 2) void gemm_mfma(
    const float* __restrict__ H, const unsigned short* __restrict__ Pjh,
    const unsigned short* __restrict__ Pjl, float* __restrict__ Pt)
{
    __shared__ unsigned short Hs[2][64 * LDSROW];

    int tid = threadIdx.x;
    int w = tid >> 6;
    int lane = tid & 63;
    int c = lane & 15;
    int q = lane >> 4;

    int b = blockIdx.x >> 2;
    int lbase = (blockIdx.x & 3) * 64;

    const float* Hbase = H + ((size_t)(b * L_ + lbase)) * HID_;

    int hrow0 = tid >> 3;          // 0..31
    int hc4   = tid & 7;           // float4 within 32-k row

    const unsigned short* pjh0 = Pjh + (size_t)(w * 32 + c) * HID_ + q * 8;
    const unsigned short* pjh1 = Pjh + (size_t)(w * 32 + 16 + c) * HID_ + q * 8;
    const unsigned short* pjl0 = Pjl + (size_t)(w * 32 + c) * HID_ + q * 8;
    const unsigned short* pjl1 = Pjl + (size_t)(w * 32 + 16 + c) * HID_ + q * 8;

    f32x4 acc[2][4] = {};

    float4 hreg[2];
    uint4 cah[2], cal[2];
    uint4 nah[2], nal[2];

    hreg[0] = *(const float4*)(Hbase + (size_t)hrow0 * HID_ + hc4 * 4);
    hreg[1] = *(const float4*)(Hbase + (size_t)(hrow0 + 32) * HID_ + hc4 * 4);
    cah[0] = *(const uint4*)(pjh0);
    cah[1] = *(const uint4*)(pjh1);
    cal[0] = *(const uint4*)(pjl0);
    cal[1] = *(const uint4*)(pjl1);
#pragma unroll
    for (int u = 0; u < 2; ++u) {
        int row = hrow0 + u * 32;
        float4 v = hreg[u];
        ushort4 h, l;
        h.x = bf_hi_trunc(v.x); l.x = f2bf_rne(v.x - bf2f(h.x));
        h.y = bf_hi_trunc(v.y); l.y = f2bf_rne(v.y - bf2f(h.y));
        h.z = bf_hi_trunc(v.z); l.z = f2bf_rne(v.z - bf2f(h.z));
        h.w = bf_hi_trunc(v.w); l.w = f2bf_rne(v.w - bf2f(h.w));
        *(ushort4*)&Hs[0][row * LDSROW + hc4 * 4]      = h;
        *(ushort4*)&Hs[0][row * LDSROW + 32 + hc4 * 4] = l;
    }
    __syncthreads();

    for (int it = 0; it < 24; ++it) {
        int cur = it & 1;
        int nxt = cur ^ 1;

        if (it + 1 < 24) {
            int k0 = (it + 1) * 32;
            hreg[0] = *(const float4*)(Hbase + (size_t)hrow0 * HID_ + k0 + hc4 * 4);
            hreg[1] = *(const float4*)(Hbase + (size_t)(hrow0 + 32) * HID_ + k0 + hc4 * 4);
            nah[0] = *(const uint4*)(pjh0 + k0);
            nah[1] = *(const uint4*)(pjh1 + k0);
            nal[0] = *(const uint4*)(pjl0 + k0);
            nal[1] = *(const uint4*)(pjl1 + k0);
        }

        bf16x8 bh[4], bl[4];
#pragma unroll
        for (int lt = 0; lt < 4; ++lt) {
            int l = lt * 16 + c;
            bh[lt] = *(const bf16x8*)&Hs[cur][l * LDSROW + q * 8];
            bl[lt] = *(const bf16x8*)&Hs[cur][l * LDSROW + 32 + q * 8];
        }
        bf16x8 ah[2], al[2];
        ah[0] = *(bf16x8*)&cah[0]; ah[1] = *(bf16x8*)&cah[1];
        al[0] = *(bf16x8*)&cal[0]; al[1] = *(bf16x8*)&cal[1];

#pragma unroll
        for (int pt = 0; pt < 2; ++pt)
#pragma unroll
        for (int lt = 0; lt < 4; ++lt) {
            acc[pt][lt] = __builtin_amdgcn_mfma_f32_16x16x32_bf16(ah[pt], bh[lt], acc[pt][lt], 0, 0, 0);
            acc[pt][lt] = __builtin_amdgcn_mfma_f32_16x16x32_bf16(ah[pt], bl[lt], acc[pt][lt], 0, 0, 0);
            acc[pt][lt] = __builtin_amdgcn_mfma_f32_16x16x32_bf16(al[pt], bh[lt], acc[pt][lt], 0, 0, 0);
        }

        if (it + 1 < 24) {
#pragma unroll
            for (int u = 0; u < 2; ++u) {
                int row = hrow0 + u * 32;
                float4 v = hreg[u];
                ushort4 h, l;
                h.x = bf_hi_trunc(v.x); l.x = f2bf_rne(v.x - bf2f(h.x));
                h.y = bf_hi_trunc(v.y); l.y = f2bf_rne(v.y - bf2f(h.y));
                h.z = bf_hi_trunc(v.z); l.z = f2bf_rne(v.z - bf2f(h.z));
                h.w = bf_hi_trunc(v.w); l.w = f2bf_rne(v.w - bf2f(h.w));
                *(ushort4*)&Hs[nxt][row * LDSROW + hc4 * 4]      = h;
                *(ushort4*)&Hs[nxt][row * LDSROW + 32 + hc4 * 4] = l;
            }
            cah[0] = nah[0]; cah[1] = nah[1];
            cal[0] = nal[0]; cal[1] = nal[1];
        }
        __syncthreads();
    }

#pragma unroll
    for (int pt = 0; pt < 2; ++pt)
#pragma unroll
    for (int lt = 0; lt < 4; ++lt)
#pragma unroll
    for (int r = 0; r < 4; ++r) {
        int p = w * 32 + pt * 16 + q * 4 + r;
        int l = lbase + lt * 16 + c;
        Pt[((size_t)(b * NPROJ_ + p)) * L_ + l] = acc[pt][lt][r];
    }
}

// ---------------------------------------------------------------------------
// Kernel A2: finalize rep (back to standalone). grid = B, 256 threads.
// ---------------------------------------------------------------------------
__global__ __launch_bounds__(256) void stats_fin(
    const float* __restrict__ H, const int* __restrict__ tt,
    const int* __restrict__ mm, const float* __restrict__ part,
    float* __restrict__ rep)
{
    int b = blockIdx.x;
    int tid = threadIdx.x;
    int t = tt[b * L_ + tid];
    int mv = mm[b * L_ + tid];
    int n0 = __syncthreads_count(t == 0 && mv == 1);
    int n1 = __syncthreads_count(t == 1 && mv == 1);
    float r0 = 1.f / fmaxf((float)n0, 1.f);
    float r1 = 1.f / fmaxf((float)n1, 1.f);

    const float* pp = part + (size_t)b * 8 * HID2_;
    for (int h = tid; h < HID_; h += 256) {
        float a0 = 0.f, a1 = 0.f;
#pragma unroll
        for (int q = 0; q < 8; ++q) {
            a0 += pp[(size_t)q * HID2_ + h];
            a1 += pp[(size_t)q * HID2_ + HID_ + h];
        }
        rep[(size_t)b * HID2_ + h] = H[(size_t)b * L_ * HID_ + h];
        rep[(size_t)b * HID2_ + HID_ + h] = a0 * r0 - a1 * r1;
    }
}

// ---------------------------------------------------------------------------
// Kernel B: wide fused head (back to one wave per (b,o); 40960 waves)
// ---------------------------------------------------------------------------
__global__ __launch_bounds__(256) void head_kernel(
    const float* __restrict__ rep, const float* __restrict__ Wc,
    const float* __restrict__ bc, const float* __restrict__ Ws,
    const float* __restrict__ bs, const float* __restrict__ gate,
    float* __restrict__ fused)
{
    int w = blockIdx.x * 4 + (threadIdx.x >> 6);
    int lane = threadIdx.x & 63;
    int b = w / (CDIM_ + SDIM_);
    int o = w % (CDIM_ + SDIM_);
    bool isC = (o < CDIM_);
    const float4* wr = (const float4*)(isC ? (Wc + (size_t)o * HID2_)
                                           : (Ws + (size_t)(o - CDIM_) * HID2_));
    const float4* rp = (const float4*)(rep + (size_t)b * HID2_);
    float acc = 0.f;
#pragma unroll
    for (int u = 0; u < 6; ++u) {
        int k4 = lane + u * 64;
        float4 a = rp[k4];
        float4 ww = wr[k4];
        acc += a.x * ww.x + a.y * ww.y + a.z * ww.z + a.w * ww.w;
    }
    for (int off = 32; off; off >>= 1) acc += __shfl_xor(acc, off, 64);
    if (lane == 0) {
        float g = 1.0f / (1.0f + expf(-gate[0]));
        float bias = isC ? bc[o] : bs[o - CDIM_];
        float scale = isC ? (1.0f - g) : g;
        fused[(size_t)b * (CDIM_ + SDIM_) + o] = (acc + bias) * scale;
    }
}

// ---------------------------------------------------------------------------
// Kernel D: merged-sort W1 distance, contiguous-element bitonic (unchanged)
// ---------------------------------------------------------------------------
__global__ __launch_bounds__(256) void ot_kernel(
    const float* __restrict__ Pt, const int* __restrict__ tt,
    const int* __restrict__ mm, float* __restrict__ dist)
{
    int w = blockIdx.x * 4 + (threadIdx.x >> 6);
    int lane = threadIdx.x & 63;
    int b = w >> 7;
    int p = w & (NPROJ_ - 1);

    float4 pv = *(const float4*)(Pt + ((size_t)(b * NPROJ_ + p)) * L_ + lane * 4);
    int4 t4 = *(const int4*)(tt + (size_t)b * L_ + lane * 4);
    int4 m4 = *(const int4*)(mm + (size_t)b * L_ + lane * 4);

    float pvals[4] = {pv.x, pv.y, pv.z, pv.w};
    int tv[4] = {t4.x, t4.y, t4.z, t4.w};
    int mv[4] = {m4.x, m4.y, m4.z, m4.w};

    unsigned key[4];
#pragma unroll
    for (int r = 0; r < 4; ++r) {
        unsigned u = __float_as_uint(pvals[r]);
        unsigned s = (u & 0x80000000u) ? ~u : (u | 0x80000000u);
        unsigned label = (mv[r] == 1) ? (unsigned)tv[r] : 2u;
        key[r] = (s & ~3u) | label;
    }

    {   // k=2, j=1
        unsigned mn0 = min(key[0], key[1]), mx0 = max(key[0], key[1]);
        key[0] = mn0; key[1] = mx0;
        unsigned mn1 = min(key[2], key[3]), mx1 = max(key[2], key[3]);
        key[2] = mx1; key[3] = mn1;
    }
#pragma unroll
    for (int k = 4; k <= 256; k <<= 1) {
        bool up = (lane & (k >> 2)) == 0;
#pragma unroll
        for (int j = k >> 1; j >= 4; j >>= 1) {
            int lj = j >> 2;
#pragma unroll
            for (int r = 0; r < 4; ++r) {
                unsigned o = (unsigned)__shfl_xor((int)key[r], lj, 64);
                bool lower = (lane & lj) == 0;
                unsigned mn = min(key[r], o), mx = max(key[r], o);
                key[r] = (lower == up) ? mn : mx;
            }
        }
        {   // j=2
            unsigned mn0 = min(key[0], key[2]), mx0 = max(key[0], key[2]);
            key[0] = up ? mn0 : mx0; key[2] = up ? mx0 : mn0;
            unsigned mn1 = min(key[1], key[3]), mx1 = max(key[1], key[3]);
            key[1] = up ? mn1 : mx1; key[3] = up ? mx1 : mn1;
        }
        {   // j=1
            unsigned mn0 = min(key[0], key[1]), mx0 = max(key[0], key[1]);
            key[0] = up ? mn0 : mx0; key[1] = up ? mx0 : mn0;
            unsigned mn1 = min(key[2], key[3]), mx1 = max(key[2], key[3]);
            key[2] = up ? mn1 : mx1; key[3] = up ? mx1 : mn1;
        }
    }

    int lab[4];
    float tval[4];
    unsigned sincl[4];
    unsigned run = 0;
#pragma unroll
    for (int r = 0; r < 4; ++r) {
        lab[r] = (int)(key[r] & 3u);
        unsigned s = key[r] & ~3u;
        unsigned u = (s & 0x80000000u) ? (s ^ 0x80000000u) : ~s;
        tval[r] = __uint_as_float(u);
        unsigned unit = ((lab[r] == 0) ? 0x10000u : 0u) | ((lab[r] == 1) ? 1u : 0u);
        run += unit;
        sincl[r] = run;
    }
    unsigned inc = run;
#pragma unroll
    for (int d = 1; d < 64; d <<= 1) {
        unsigned t = (unsigned)__shfl_up((int)inc, d, 64);
        if (lane >= d) inc += t;
    }
    unsigned ex = inc - run;
    unsigned total = (unsigned)__shfl((int)inc, 63, 64);
    int n0 = (int)(total >> 16), n1 = (int)(total & 0xffffu);
    int m = (n0 < n1) ? n0 : n1;

    float ssum = 0.f;
#pragma unroll
    for (int r = 0; r < 4; ++r) {
        unsigned C = ex + sincl[r];
        int c0 = (int)(C >> 16), c1 = (int)(C & 0xffffu);
        int s0 = (lab[r] == 0), s1 = (lab[r] == 1);
        int wi = abs(min(c0, m) - min(c1, m));
        int wp = abs(min(c0 - s0, m) - min(c1 - s1, m));
        ssum += tval[r] * (float)(wp - wi);
    }
    for (int off = 32; off; off >>= 1) ssum += __shfl_xor(ssum, off, 64);
    if (lane == 0) dist[b * NPROJ_ + p] = ssum / (float)((m > 1) ? m : 1);
}

// ---------------------------------------------------------------------------
// Kernel E: max over p, layernorm, classifier (unchanged)
// ---------------------------------------------------------------------------
__global__ __launch_bounds__(64) void final_kernel(
    const float* __restrict__ fused, const float* __restrict__ dist,
    const float* __restrict__ ln_g, const float* __restrict__ ln_b,
    const float* __restrict__ Wcls, const float* __restrict__ bcls,
    float* __restrict__ out)
{
    int b = blockIdx.x;
    int lane = threadIdx.x;

    float mx = fmaxf(dist[b * NPROJ_ + lane], dist[b * NPROJ_ + 64 + lane]);
    for (int off = 32; off; off >>= 1) mx = fmaxf(mx, __shfl_xor(mx, off, 64));

    float fv[6];
    float sum = 0.f, sq = 0.f;
#pragma unroll
    for (int u = 0; u < 6; ++u) {
        int j = lane + u * 64;
        float x = 0.f;
        if (j < CDIM_ + SDIM_) x = fused[(size_t)b * (CDIM_ + SDIM_) + j];
        else if (j == CDIM_ + SDIM_) x = mx;
        fv[u] = x;
        if (j < FDIM_) { sum += x; sq += x * x; }
    }
    for (int off = 32; off; off >>= 1) {
        sum += __shfl_xor(sum, off, 64);
        sq  += __shfl_xor(sq,  off, 64);
    }
    float mu = sum / (float)FDIM_;
    float var = sq / (float)FDIM_ - mu * mu;
    float inv = rsqrtf(var + 1e-5f);

    float d0 = 0.f, d1 = 0.f;
#pragma unroll
    for (int u = 0; u < 6; ++u) {
        int j = lane + u * 64;
        if (j < FDIM_) {
            float nx = (fv[u] - mu) * inv * ln_g[j] + ln_b[j];
            d0 += nx * Wcls[j];
            d1 += nx * Wcls[FDIM_ + j];
        }
    }
    for (int off = 32; off; off >>= 1) {
        d0 += __shfl_xor(d0, off, 64);
        d1 += __shfl_xor(d1, off, 64);
    }
    if (lane == 0) {
        out[b * 2 + 0] = d0 + bcls[0];
        out[b * 2 + 1] = d1 + bcls[1];
    }
}

// ---------------------------------------------------------------------------
extern "C" void kernel_launch(void* const* d_in, const int* in_sizes, int n_in,
                              void* d_out, int out_size, void* d_ws, size_t ws_size,
                              hipStream_t stream)
{
    const float* H    = (const float*)d_in[0];
    const int*   tt   = (const int*)d_in[1];
    const int*   mm   = (const int*)d_in[2];
    const float* Wc   = (const float*)d_in[3];
    const float* bc   = (const float*)d_in[4];
    const float* Ws   = (const float*)d_in[5];
    const float* bs   = (const float*)d_in[6];
    const float* gate = (const float*)d_in[7];
    const float* ln_g = (const float*)d_in[8];
    const float* ln_b = (const float*)d_in[9];
    const float* Wcls = (const float*)d_in[10];
    const float* bcls = (const float*)d_in[11];
    const float* Pd   = (const float*)d_in[12];
    float* out = (float*)d_out;

    float* ws = (float*)d_ws;
    float* Pt    = ws;                                       // 4194304 fl
    float* part  = Pt + (size_t)B_ * NPROJ_ * L_;            // 128*8*1536 fl
    float* rep   = part + (size_t)B_ * 8 * HID2_;            // 128*1536 fl
    float* fused = rep + (size_t)B_ * HID2_;                 // 128*320 fl
    float* dist  = fused + (size_t)B_ * (CDIM_ + SDIM_);     // 128*128 fl
    unsigned short* Pjh = (unsigned short*)(dist + (size_t)B_ * NPROJ_);
    unsigned short* Pjl = Pjh + (size_t)NPROJ_ * HID_;

    pre_kernel<<<128 + B_ * 8, 192, 0, stream>>>(Pd, Pjh, Pjl, H, tt, mm, part);
    gemm_mfma<<<B_ * 4, 256, 0, stream>>>(H, Pjh, Pjl, Pt);   // H L3-hot from pre
    stats_fin<<<B_, 256, 0, stream>>>(H, tt, mm, part, rep);
    head_kernel<<<B_ * (CDIM_ + SDIM_) / 4, 256, 0, stream>>>(rep, Wc, bc, Ws, bs, gate, fused);
    ot_kernel<<<B_ * NPROJ_ / 4, 256, 0, stream>>>(Pt, tt, mm, dist);
    final_kernel<<<B_, 64, 0, stream>>>(fused, dist, ln_g, ln_b, Wcls, bcls, out);
}

// Round 9
// 246.599 us; speedup vs baseline: 1.3465x; 1.0128x over previous
//
#include <hip/hip_runtime.h>
#include <cmath>

#define B_   128
#define L_   256
#define HID_ 768
#define HID2_ 1536
#define CDIM_ 192
#define SDIM_ 128
#define NPROJ_ 128
#define FDIM_ 321

typedef __attribute__((ext_vector_type(8))) short bf16x8;
typedef __attribute__((ext_vector_type(4))) float f32x4;

__device__ inline unsigned short bf_hi_trunc(float x) {
    return (unsigned short)(__float_as_uint(x) >> 16);
}
__device__ inline float bf2f(unsigned short s) {
    return __uint_as_float(((unsigned int)s) << 16);
}
__device__ inline unsigned short f2bf_rne(float x) {
    unsigned int u = __float_as_uint(x);
    unsigned int r = (u + 0x7fff + ((u >> 16) & 1)) >> 16;
    return (unsigned short)r;
}

// ---------------------------------------------------------------------------
// Kernel P: fused pre-pass. Blocks [0,128): proj_dirs fp32 -> bf16 hi/lo.
// Blocks [128,1152): stats partial masked sums (32 l-rows each).
// ---------------------------------------------------------------------------
__global__ __launch_bounds__(192) void pre_kernel(
    const float* __restrict__ Pd, unsigned short* __restrict__ Pjh,
    unsigned short* __restrict__ Pjl,
    const float* __restrict__ H, const int* __restrict__ tt,
    const int* __restrict__ mm, float* __restrict__ part)
{
    int tid = threadIdx.x;
    if (blockIdx.x < 128) {
        int i = blockIdx.x * 192 + tid;       // float4 index, total 24576
        float4 v = ((const float4*)Pd)[i];
        ushort4 h, l;
        h.x = bf_hi_trunc(v.x); l.x = f2bf_rne(v.x - bf2f(h.x));
        h.y = bf_hi_trunc(v.y); l.y = f2bf_rne(v.y - bf2f(h.y));
        h.z = bf_hi_trunc(v.z); l.z = f2bf_rne(v.z - bf2f(h.z));
        h.w = bf_hi_trunc(v.w); l.w = f2bf_rne(v.w - bf2f(h.w));
        ((ushort4*)Pjh)[i] = h;
        ((ushort4*)Pjl)[i] = l;
        return;
    }
    int bid = blockIdx.x - 128;
    int b  = bid >> 3;
    int pr = bid & 7;

    __shared__ float sf0[32], sf1[32];
    if (tid < 32) {
        int l = pr * 32 + tid;
        int t = tt[b * L_ + l];
        int mv = mm[b * L_ + l];
        sf0[tid] = (t == 0 && mv == 1) ? 1.f : 0.f;
        sf1[tid] = (t == 1 && mv == 1) ? 1.f : 0.f;
    }
    __syncthreads();

    const float* Hb = H + ((size_t)(b * L_ + pr * 32)) * HID_;
    float4 a0 = make_float4(0.f, 0.f, 0.f, 0.f);
    float4 a1 = make_float4(0.f, 0.f, 0.f, 0.f);
    for (int l = 0; l < 32; ++l) {
        float4 x = *(const float4*)(Hb + (size_t)l * HID_ + tid * 4);
        float f0 = sf0[l], f1 = sf1[l];
        a0.x += x.x * f0; a0.y += x.y * f0; a0.z += x.z * f0; a0.w += x.w * f0;
        a1.x += x.x * f1; a1.y += x.y * f1; a1.z += x.z * f1; a1.w += x.w * f1;
    }
    float* dst = part + ((size_t)(b * 8 + pr)) * HID2_;
    *(float4*)(dst + tid * 4) = a0;
    *(float4*)(dst + HID_ + tid * 4) = a1;
}

// ---------------------------------------------------------------------------
// Kernel C: split-bf16 MFMA GEMM v3, launch_bounds(256,4) to cap VGPR<=128
// (occupancy 3 -> 4 waves/SIMD; LDS 18.4 KB x 4 blocks = 74 KB fits).
// ---------------------------------------------------------------------------
#define LDSROW 72   // bf16 per H row: [0:32) hi | [32:64) lo | pad
__global__ __launch_bounds__(256, 4) void gemm_mfma(
    const float* __restrict__ H, const unsigned short* __restrict__ Pjh,
    const unsigned short* __restrict__ Pjl, float* __restrict__ Pt)
{
    __shared__ unsigned short Hs[2][64 * LDSROW];

    int tid = threadIdx.x;
    int w = tid >> 6;
    int lane = tid & 63;
    int c = lane & 15;
    int q = lane >> 4;

    int b = blockIdx.x >> 2;
    int lbase = (blockIdx.x & 3) * 64;

    const float* Hbase = H + ((size_t)(b * L_ + lbase)) * HID_;

    int hrow0 = tid >> 3;          // 0..31
    int hc4   = tid & 7;           // float4 within 32-k row

    const unsigned short* pjh0 = Pjh + (size_t)(w * 32 + c) * HID_ + q * 8;
    const unsigned short* pjh1 = Pjh + (size_t)(w * 32 + 16 + c) * HID_ + q * 8;
    const unsigned short* pjl0 = Pjl + (size_t)(w * 32 + c) * HID_ + q * 8;
    const unsigned short* pjl1 = Pjl + (size_t)(w * 32 + 16 + c) * HID_ + q * 8;

    f32x4 acc[2][4] = {};

    float4 hreg[2];
    uint4 cah[2], cal[2];
    uint4 nah[2], nal[2];

    hreg[0] = *(const float4*)(Hbase + (size_t)hrow0 * HID_ + hc4 * 4);
    hreg[1] = *(const float4*)(Hbase + (size_t)(hrow0 + 32) * HID_ + hc4 * 4);
    cah[0] = *(const uint4*)(pjh0);
    cah[1] = *(const uint4*)(pjh1);
    cal[0] = *(const uint4*)(pjl0);
    cal[1] = *(const uint4*)(pjl1);
#pragma unroll
    for (int u = 0; u < 2; ++u) {
        int row = hrow0 + u * 32;
        float4 v = hreg[u];
        ushort4 h, l;
        h.x = bf_hi_trunc(v.x); l.x = f2bf_rne(v.x - bf2f(h.x));
        h.y = bf_hi_trunc(v.y); l.y = f2bf_rne(v.y - bf2f(h.y));
        h.z = bf_hi_trunc(v.z); l.z = f2bf_rne(v.z - bf2f(h.z));
        h.w = bf_hi_trunc(v.w); l.w = f2bf_rne(v.w - bf2f(h.w));
        *(ushort4*)&Hs[0][row * LDSROW + hc4 * 4]      = h;
        *(ushort4*)&Hs[0][row * LDSROW + 32 + hc4 * 4] = l;
    }
    __syncthreads();

    for (int it = 0; it < 24; ++it) {
        int cur = it & 1;
        int nxt = cur ^ 1;

        if (it + 1 < 24) {
            int k0 = (it + 1) * 32;
            hreg[0] = *(const float4*)(Hbase + (size_t)hrow0 * HID_ + k0 + hc4 * 4);
            hreg[1] = *(const float4*)(Hbase + (size_t)(hrow0 + 32) * HID_ + k0 + hc4 * 4);
            nah[0] = *(const uint4*)(pjh0 + k0);
            nah[1] = *(const uint4*)(pjh1 + k0);
            nal[0] = *(const uint4*)(pjl0 + k0);
            nal[1] = *(const uint4*)(pjl1 + k0);
        }

        bf16x8 bh[4], bl[4];
#pragma unroll
        for (int lt = 0; lt < 4; ++lt) {
            int l = lt * 16 + c;
            bh[lt] = *(const bf16x8*)&Hs[cur][l * LDSROW + q * 8];
            bl[lt] = *(const bf16x8*)&Hs[cur][l * LDSROW + 32 + q * 8];
        }
        bf16x8 ah[2], al[2];
        ah[0] = *(bf16x8*)&cah[0]; ah[1] = *(bf16x8*)&cah[1];
        al[0] = *(bf16x8*)&cal[0]; al[1] = *(bf16x8*)&cal[1];

#pragma unroll
        for (int pt = 0; pt < 2; ++pt)
#pragma unroll
        for (int lt = 0; lt < 4; ++lt) {
            acc[pt][lt] = __builtin_amdgcn_mfma_f32_16x16x32_bf16(ah[pt], bh[lt], acc[pt][lt], 0, 0, 0);
            acc[pt][lt] = __builtin_amdgcn_mfma_f32_16x16x32_bf16(ah[pt], bl[lt], acc[pt][lt], 0, 0, 0);
            acc[pt][lt] = __builtin_amdgcn_mfma_f32_16x16x32_bf16(al[pt], bh[lt], acc[pt][lt], 0, 0, 0);
        }

        if (it + 1 < 24) {
#pragma unroll
            for (int u = 0; u < 2; ++u) {
                int row = hrow0 + u * 32;
                float4 v = hreg[u];
                ushort4 h, l;
                h.x = bf_hi_trunc(v.x); l.x = f2bf_rne(v.x - bf2f(h.x));
                h.y = bf_hi_trunc(v.y); l.y = f2bf_rne(v.y - bf2f(h.y));
                h.z = bf_hi_trunc(v.z); l.z = f2bf_rne(v.z - bf2f(h.z));
                h.w = bf_hi_trunc(v.w); l.w = f2bf_rne(v.w - bf2f(h.w));
                *(ushort4*)&Hs[nxt][row * LDSROW + hc4 * 4]      = h;
                *(ushort4*)&Hs[nxt][row * LDSROW + 32 + hc4 * 4] = l;
            }
            cah[0] = nah[0]; cah[1] = nah[1];
            cal[0] = nal[0]; cal[1] = nal[1];
        }
        __syncthreads();
    }

#pragma unroll
    for (int pt = 0; pt < 2; ++pt)
#pragma unroll
    for (int lt = 0; lt < 4; ++lt)
#pragma unroll
    for (int r = 0; r < 4; ++r) {
        int p = w * 32 + pt * 16 + q * 4 + r;
        int l = lbase + lt * 16 + c;
        Pt[((size_t)(b * NPROJ_ + p)) * L_ + l] = acc[pt][lt][r];
    }
}

// ---------------------------------------------------------------------------
// Kernel A2: finalize rep. grid = B, 256 threads. (unchanged)
// ---------------------------------------------------------------------------
__global__ __launch_bounds__(256) void stats_fin(
    const float* __restrict__ H, const int* __restrict__ tt,
    const int* __restrict__ mm, const float* __restrict__ part,
    float* __restrict__ rep)
{
    int b = blockIdx.x;
    int tid = threadIdx.x;
    int t = tt[b * L_ + tid];
    int mv = mm[b * L_ + tid];
    int n0 = __syncthreads_count(t == 0 && mv == 1);
    int n1 = __syncthreads_count(t == 1 && mv == 1);
    float r0 = 1.f / fmaxf((float)n0, 1.f);
    float r1 = 1.f / fmaxf((float)n1, 1.f);

    const float* pp = part + (size_t)b * 8 * HID2_;
    for (int h = tid; h < HID_; h += 256) {
        float a0 = 0.f, a1 = 0.f;
#pragma unroll
        for (int q = 0; q < 8; ++q) {
            a0 += pp[(size_t)q * HID2_ + h];
            a1 += pp[(size_t)q * HID2_ + HID_ + h];
        }
        rep[(size_t)b * HID2_ + h] = H[(size_t)b * L_ * HID_ + h];
        rep[(size_t)b * HID2_ + HID_ + h] = a0 * r0 - a1 * r1;
    }
}

// ---------------------------------------------------------------------------
// Kernel B: head with LDS-staged rep. grid = B*8 = 1024 blocks, 256 thr.
// Block: b = bid>>3, outputs ochunk = (bid&7)*40 .. +40. 4 waves x 10 rounds.
// rep global traffic 245 MB -> 6 MB; W traffic unchanged; 4096 waves (wide).
// ---------------------------------------------------------------------------
__global__ __launch_bounds__(256) void head_kernel(
    const float* __restrict__ rep, const float* __restrict__ Wc,
    const float* __restrict__ bc, const float* __restrict__ Ws,
    const float* __restrict__ bs, const float* __restrict__ gate,
    float* __restrict__ fused)
{
    __shared__ float srep[HID2_];

    int b = blockIdx.x >> 3;
    int ochunk = (blockIdx.x & 7) * 40;
    int tid = threadIdx.x;

    for (int i = tid; i < HID2_ / 4; i += 256)
        *(float4*)&srep[i * 4] = *(const float4*)&rep[(size_t)b * HID2_ + i * 4];
    __syncthreads();

    int w = tid >> 6;
    int lane = tid & 63;
    float g = 1.0f / (1.0f + expf(-gate[0]));

#pragma unroll
    for (int r = 0; r < 10; ++r) {
        int o = ochunk + r * 4 + w;
        bool isC = (o < CDIM_);
        const float4* wr = (const float4*)(isC ? (Wc + (size_t)o * HID2_)
                                               : (Ws + (size_t)(o - CDIM_) * HID2_));
        float acc = 0.f;
#pragma unroll
        for (int u = 0; u < 6; ++u) {
            int k4 = lane + u * 64;
            float4 a = *(const float4*)&srep[k4 * 4];
            float4 ww = wr[k4];
            acc += a.x * ww.x + a.y * ww.y + a.z * ww.z + a.w * ww.w;
        }
        for (int off = 32; off; off >>= 1) acc += __shfl_xor(acc, off, 64);
        if (lane == 0) {
            float bias = isC ? bc[o] : bs[o - CDIM_];
            float scale = isC ? (1.0f - g) : g;
            fused[(size_t)b * (CDIM_ + SDIM_) + o] = (acc + bias) * scale;
        }
    }
}

// ---------------------------------------------------------------------------
// Kernel D: merged-sort W1 distance, contiguous-element bitonic (unchanged)
// ---------------------------------------------------------------------------
__global__ __launch_bounds__(256) void ot_kernel(
    const float* __restrict__ Pt, const int* __restrict__ tt,
    const int* __restrict__ mm, float* __restrict__ dist)
{
    int w = blockIdx.x * 4 + (threadIdx.x >> 6);
    int lane = threadIdx.x & 63;
    int b = w >> 7;
    int p = w & (NPROJ_ - 1);

    float4 pv = *(const float4*)(Pt + ((size_t)(b * NPROJ_ + p)) * L_ + lane * 4);
    int4 t4 = *(const int4*)(tt + (size_t)b * L_ + lane * 4);
    int4 m4 = *(const int4*)(mm + (size_t)b * L_ + lane * 4);

    float pvals[4] = {pv.x, pv.y, pv.z, pv.w};
    int tv[4] = {t4.x, t4.y, t4.z, t4.w};
    int mv[4] = {m4.x, m4.y, m4.z, m4.w};

    unsigned key[4];
#pragma unroll
    for (int r = 0; r < 4; ++r) {
        unsigned u = __float_as_uint(pvals[r]);
        unsigned s = (u & 0x80000000u) ? ~u : (u | 0x80000000u);
        unsigned label = (mv[r] == 1) ? (unsigned)tv[r] : 2u;
        key[r] = (s & ~3u) | label;
    }

    {   // k=2, j=1
        unsigned mn0 = min(key[0], key[1]), mx0 = max(key[0], key[1]);
        key[0] = mn0; key[1] = mx0;
        unsigned mn1 = min(key[2], key[3]), mx1 = max(key[2], key[3]);
        key[2] = mx1; key[3] = mn1;
    }
#pragma unroll
    for (int k = 4; k <= 256; k <<= 1) {
        bool up = (lane & (k >> 2)) == 0;
#pragma unroll
        for (int j = k >> 1; j >= 4; j >>= 1) {
            int lj = j >> 2;
#pragma unroll
            for (int r = 0; r < 4; ++r) {
                unsigned o = (unsigned)__shfl_xor((int)key[r], lj, 64);
                bool lower = (lane & lj) == 0;
                unsigned mn = min(key[r], o), mx = max(key[r], o);
                key[r] = (lower == up) ? mn : mx;
            }
        }
        {   // j=2
            unsigned mn0 = min(key[0], key[2]), mx0 = max(key[0], key[2]);
            key[0] = up ? mn0 : mx0; key[2] = up ? mx0 : mn0;
            unsigned mn1 = min(key[1], key[3]), mx1 = max(key[1], key[3]);
            key[1] = up ? mn1 : mx1; key[3] = up ? mx1 : mn1;
        }
        {   // j=1
            unsigned mn0 = min(key[0], key[1]), mx0 = max(key[0], key[1]);
            key[0] = up ? mn0 : mx0; key[1] = up ? mx0 : mn0;
            unsigned mn1 = min(key[2], key[3]), mx1 = max(key[2], key[3]);
            key[2] = up ? mn1 : mx1; key[3] = up ? mx1 : mn1;
        }
    }

    int lab[4];
    float tval[4];
    unsigned sincl[4];
    unsigned run = 0;
#pragma unroll
    for (int r = 0; r < 4; ++r) {
        lab[r] = (int)(key[r] & 3u);
        unsigned s = key[r] & ~3u;
        unsigned u = (s & 0x80000000u) ? (s ^ 0x80000000u) : ~s;
        tval[r] = __uint_as_float(u);
        unsigned unit = ((lab[r] == 0) ? 0x10000u : 0u) | ((lab[r] == 1) ? 1u : 0u);
        run += unit;
        sincl[r] = run;
    }
    unsigned inc = run;
#pragma unroll
    for (int d = 1; d < 64; d <<= 1) {
        unsigned t = (unsigned)__shfl_up((int)inc, d, 64);
        if (lane >= d) inc += t;
    }
    unsigned ex = inc - run;
    unsigned total = (unsigned)__shfl((int)inc, 63, 64);
    int n0 = (int)(total >> 16), n1 = (int)(total & 0xffffu);
    int m = (n0 < n1) ? n0 : n1;

    float ssum = 0.f;
#pragma unroll
    for (int r = 0; r < 4; ++r) {
        unsigned C = ex + sincl[r];
        int c0 = (int)(C >> 16), c1 = (int)(C & 0xffffu);
        int s0 = (lab[r] == 0), s1 = (lab[r] == 1);
        int wi = abs(min(c0, m) - min(c1, m));
        int wp = abs(min(c0 - s0, m) - min(c1 - s1, m));
        ssum += tval[r] * (float)(wp - wi);
    }
    for (int off = 32; off; off >>= 1) ssum += __shfl_xor(ssum, off, 64);
    if (lane == 0) dist[b * NPROJ_ + p] = ssum / (float)((m > 1) ? m : 1);
}

// ---------------------------------------------------------------------------
// Kernel E: max over p, layernorm, classifier (unchanged)
// ---------------------------------------------------------------------------
__global__ __launch_bounds__(64) void final_kernel(
    const float* __restrict__ fused, const float* __restrict__ dist,
    const float* __restrict__ ln_g, const float* __restrict__ ln_b,
    const float* __restrict__ Wcls, const float* __restrict__ bcls,
    float* __restrict__ out)
{
    int b = blockIdx.x;
    int lane = threadIdx.x;

    float mx = fmaxf(dist[b * NPROJ_ + lane], dist[b * NPROJ_ + 64 + lane]);
    for (int off = 32; off; off >>= 1) mx = fmaxf(mx, __shfl_xor(mx, off, 64));

    float fv[6];
    float sum = 0.f, sq = 0.f;
#pragma unroll
    for (int u = 0; u < 6; ++u) {
        int j = lane + u * 64;
        float x = 0.f;
        if (j < CDIM_ + SDIM_) x = fused[(size_t)b * (CDIM_ + SDIM_) + j];
        else if (j == CDIM_ + SDIM_) x = mx;
        fv[u] = x;
        if (j < FDIM_) { sum += x; sq += x * x; }
    }
    for (int off = 32; off; off >>= 1) {
        sum += __shfl_xor(sum, off, 64);
        sq  += __shfl_xor(sq,  off, 64);
    }
    float mu = sum / (float)FDIM_;
    float var = sq / (float)FDIM_ - mu * mu;
    float inv = rsqrtf(var + 1e-5f);

    float d0 = 0.f, d1 = 0.f;
#pragma unroll
    for (int u = 0; u < 6; ++u) {
        int j = lane + u * 64;
        if (j < FDIM_) {
            float nx = (fv[u] - mu) * inv * ln_g[j] + ln_b[j];
            d0 += nx * Wcls[j];
            d1 += nx * Wcls[FDIM_ + j];
        }
    }
    for (int off = 32; off; off >>= 1) {
        d0 += __shfl_xor(d0, off, 64);
        d1 += __shfl_xor(d1, off, 64);
    }
    if (lane == 0) {
        out[b * 2 + 0] = d0 + bcls[0];
        out[b * 2 + 1] = d1 + bcls[1];
    }
}

// ---------------------------------------------------------------------------
extern "C" void kernel_launch(void* const* d_in, const int* in_sizes, int n_in,
                              void* d_out, int out_size, void* d_ws, size_t ws_size,
                              hipStream_t stream)
{
    const float* H    = (const float*)d_in[0];
    const int*   tt   = (const int*)d_in[1];
    const int*   mm   = (const int*)d_in[2];
    const float* Wc   = (const float*)d_in[3];
    const float* bc   = (const float*)d_in[4];
    const float* Ws   = (const float*)d_in[5];
    const float* bs   = (const float*)d_in[6];
    const float* gate = (const float*)d_in[7];
    const float* ln_g = (const float*)d_in[8];
    const float* ln_b = (const float*)d_in[9];
    const float* Wcls = (const float*)d_in[10];
    const float* bcls = (const float*)d_in[11];
    const float* Pd   = (const float*)d_in[12];
    float* out = (float*)d_out;

    float* ws = (float*)d_ws;
    float* Pt    = ws;                                       // 4194304 fl
    float* part  = Pt + (size_t)B_ * NPROJ_ * L_;            // 128*8*1536 fl
    float* rep   = part + (size_t)B_ * 8 * HID2_;            // 128*1536 fl
    float* fused = rep + (size_t)B_ * HID2_;                 // 128*320 fl
    float* dist  = fused + (size_t)B_ * (CDIM_ + SDIM_);     // 128*128 fl
    unsigned short* Pjh = (unsigned short*)(dist + (size_t)B_ * NPROJ_);
    unsigned short* Pjl = Pjh + (size_t)NPROJ_ * HID_;

    pre_kernel<<<128 + B_ * 8, 192, 0, stream>>>(Pd, Pjh, Pjl, H, tt, mm, part);
    gemm_mfma<<<B_ * 4, 256, 0, stream>>>(H, Pjh, Pjl, Pt);   // H L3-hot from pre
    stats_fin<<<B_, 256, 0, stream>>>(H, tt, mm, part, rep);
    head_kernel<<<B_ * 8, 256, 0, stream>>>(rep, Wc, bc, Ws, bs, gate, fused);
    ot_kernel<<<B_ * NPROJ_ / 4, 256, 0, stream>>>(Pt, tt, mm, dist);
    final_kernel<<<B_, 64, 0, stream>>>(fused, dist, ln_g, ln_b, Wcls, bcls, out);
}